// Round 2
// baseline (406.989 us; speedup 1.0000x reference)
//
#include <hip/hip_runtime.h>

#define BQ  8
#define NQ  100
#define HWP 65536
#define TILE 128
#define KST  64

typedef float  f32x4  __attribute__((ext_vector_type(4)));
typedef __bf16 bf16x8 __attribute__((ext_vector_type(8)));

struct LD { float4 x, y; };

__device__ __forceinline__ uint32_t pk2(float a, float b) {
    // RNE fp32 -> bf16, packed pair
    uint32_t ua = __builtin_bit_cast(uint32_t, a);
    uint32_t ub = __builtin_bit_cast(uint32_t, b);
    ua += 0x7FFFu + ((ua >> 16) & 1u);
    ub += 0x7FFFu + ((ub >> 16) & 1u);
    return (ua >> 16) | (ub & 0xFFFF0000u);
}

__device__ __forceinline__ LD ldrow(const float* __restrict__ base, int row, int pofs) {
    LD r;
    if (row < NQ) {
        const float4* p = (const float4*)(base + (size_t)row * HWP + pofs);
        r.x = p[0];
        r.y = p[1];
    } else {
        r.x = make_float4(0.f, 0.f, 0.f, 0.f);
        r.y = make_float4(0.f, 0.f, 0.f, 0.f);
    }
    return r;
}

__device__ __forceinline__ void strow(unsigned short* buf, int row, int oct, const LD& v) {
    // XOR swizzle (8-elem granularity) kills 128B-row-stride bank conflicts
    const int col = ((oct ^ (row & 7)) << 3);
    uint4 u;
    u.x = pk2(v.x.x, v.x.y);
    u.y = pk2(v.x.z, v.x.w);
    u.z = pk2(v.y.x, v.y.y);
    u.w = pk2(v.y.z, v.y.w);
    *(uint4*)(buf + row * KST + col) = u;
}

__device__ __forceinline__ float sqsum(const LD& v) {
    return v.x.x*v.x.x + v.x.y*v.x.y + v.x.z*v.x.z + v.x.w*v.x.w
         + v.y.x*v.y.x + v.y.y*v.y.y + v.y.z*v.y.z + v.y.w*v.y.w;
}

__device__ __forceinline__ void mfma_step(const unsigned short* __restrict__ rA,
                                          const unsigned short* __restrict__ rB,
                                          int lane, int wr, int wc,
                                          f32x4 (&acc)[2][4])
{
    #pragma unroll
    for (int s = 0; s < 2; ++s) {
        bf16x8 af[2];
        bf16x8 bfr[4];
        #pragma unroll
        for (int m = 0; m < 2; ++m) {
            const int row = wr * 32 + m * 16 + (lane & 15);
            const int col = (s * 32 + (lane >> 4) * 8) ^ ((row & 7) << 3);
            af[m] = *(const bf16x8*)(rA + row * KST + col);
        }
        #pragma unroll
        for (int n = 0; n < 4; ++n) {
            const int row = wc * 64 + n * 16 + (lane & 15);
            const int col = (s * 32 + (lane >> 4) * 8) ^ ((row & 7) << 3);
            bfr[n] = *(const bf16x8*)(rB + row * KST + col);
        }
        #pragma unroll
        for (int m = 0; m < 2; ++m)
            #pragma unroll
            for (int n = 0; n < 4; ++n)
                acc[m][n] = __builtin_amdgcn_mfma_f32_16x16x32_bf16(
                    af[m], bfr[n], acc[m][n], 0, 0, 0);
    }
}

// One block = (batch, P-chunk). Padded 128x128 partial Gram tile over its
// 1024-wide chunk + per-row sum-of-squares. 2-deep register prefetch,
// double-buffered LDS, one barrier per K-step, 2 blocks/CU.
__global__ __launch_bounds__(512, 4) void matcher_gemm(
    const float* __restrict__ mp, const float* __restrict__ mg,
    float* __restrict__ dotp, float* __restrict__ normA, float* __restrict__ normB,
    int NC, int NIT)
{
    __shared__ __align__(16) unsigned short lds_buf[2][2][TILE * KST];

    const int blk  = blockIdx.x;
    const int b    = blk / NC;
    const int slot = blk - b * NC;
    const int p0   = slot * NIT * KST;

    const int t    = threadIdx.x;
    const int row0 = t >> 3;      // 0..63 (also handles row0+64)
    const int oct  = t & 7;       // 8-float column octant
    const int lane = t & 63;
    const int w    = t >> 6;      // wave 0..7
    const int wr   = w >> 1;      // 0..3 -> 32-row strip
    const int wc   = w & 1;       // 0..1 -> 64-col strip

    const float* Ag = mp + (size_t)b * NQ * HWP;
    const float* Bg = mg + (size_t)b * NQ * HWP;

    f32x4 acc[2][4] = {};
    float nA0 = 0.f, nA1 = 0.f, nB0 = 0.f, nB1 = 0.f;

    // two named prefetch stages (no runtime-indexed reg arrays — rule #20)
    LD aA0 = ldrow(Ag, row0,      p0 + oct * 8);
    LD aA1 = ldrow(Ag, row0 + 64, p0 + oct * 8);
    LD bA0 = ldrow(Bg, row0,      p0 + oct * 8);
    LD bA1 = ldrow(Bg, row0 + 64, p0 + oct * 8);
    LD aB0 = ldrow(Ag, row0,      p0 + KST + oct * 8);
    LD aB1 = ldrow(Ag, row0 + 64, p0 + KST + oct * 8);
    LD bB0 = ldrow(Bg, row0,      p0 + KST + oct * 8);
    LD bB1 = ldrow(Bg, row0 + 64, p0 + KST + oct * 8);

    for (int it = 0; it < NIT; it += 2) {
        // ---- even K-step: stage A -> buf0 ----
        strow(lds_buf[0][0], row0,      oct, aA0);
        strow(lds_buf[0][0], row0 + 64, oct, aA1);
        strow(lds_buf[0][1], row0,      oct, bA0);
        strow(lds_buf[0][1], row0 + 64, oct, bA1);
        nA0 += sqsum(aA0); nA1 += sqsum(aA1);
        nB0 += sqsum(bA0); nB1 += sqsum(bA1);
        if (it + 2 < NIT) {
            const int pofs = p0 + (it + 2) * KST + oct * 8;
            aA0 = ldrow(Ag, row0,      pofs);
            aA1 = ldrow(Ag, row0 + 64, pofs);
            bA0 = ldrow(Bg, row0,      pofs);
            bA1 = ldrow(Bg, row0 + 64, pofs);
        }
        __syncthreads();
        mfma_step(lds_buf[0][0], lds_buf[0][1], lane, wr, wc, acc);

        // ---- odd K-step: stage B -> buf1 ----
        strow(lds_buf[1][0], row0,      oct, aB0);
        strow(lds_buf[1][0], row0 + 64, oct, aB1);
        strow(lds_buf[1][1], row0,      oct, bB0);
        strow(lds_buf[1][1], row0 + 64, oct, bB1);
        nA0 += sqsum(aB0); nA1 += sqsum(aB1);
        nB0 += sqsum(bB0); nB1 += sqsum(bB1);
        if (it + 3 < NIT) {
            const int pofs = p0 + (it + 3) * KST + oct * 8;
            aB0 = ldrow(Ag, row0,      pofs);
            aB1 = ldrow(Ag, row0 + 64, pofs);
            bB0 = ldrow(Bg, row0,      pofs);
            bB1 = ldrow(Bg, row0 + 64, pofs);
        }
        __syncthreads();
        mfma_step(lds_buf[1][0], lds_buf[1][1], lane, wr, wc, acc);
    }

    // reduce per-row norms across the 8 octant threads (contiguous lanes)
    #pragma unroll
    for (int m = 1; m < 8; m <<= 1) {
        nA0 += __shfl_xor(nA0, m);
        nA1 += __shfl_xor(nA1, m);
        nB0 += __shfl_xor(nB0, m);
        nB1 += __shfl_xor(nB1, m);
    }
    if (oct == 0) {
        float* nap = normA + (size_t)blk * TILE;
        float* nbp = normB + (size_t)blk * TILE;
        nap[row0] = nA0; nap[row0 + 64] = nA1;
        nbp[row0] = nB0; nbp[row0 + 64] = nB1;
    }

    // C/D layout (HW-verified): col = lane&15, row = (lane>>4)*4 + reg
    float* dp = dotp + (size_t)blk * (TILE * TILE);
    const int ccol = lane & 15;
    const int crow = (lane >> 4) * 4;
    #pragma unroll
    for (int m = 0; m < 2; ++m) {
        #pragma unroll
        for (int n = 0; n < 4; ++n) {
            const int gr = wr * 32 + m * 16 + crow;
            const int gc = wc * 64 + n * 16 + ccol;
            #pragma unroll
            for (int j = 0; j < 4; ++j)
                dp[(size_t)(gr + j) * TILE + gc] = acc[m][n][j];
        }
    }
}

// Reduce chunk partials, apply class-agreement term and dice division.
__global__ __launch_bounds__(256) void matcher_finalize(
    const float* __restrict__ y_p, const float* __restrict__ y_gt,
    const float* __restrict__ dotp, const float* __restrict__ normA,
    const float* __restrict__ normB, float* __restrict__ out, int NC)
{
    __shared__ float sA[TILE];
    __shared__ float sB[TILE];
    const int b    = blockIdx.x >> 4;
    const int part = blockIdx.x & 15;
    const int t    = threadIdx.x;

    if (t < TILE) {
        float s = 0.f;
        for (int c = 0; c < NC; ++c) s += normA[(size_t)(b * NC + c) * TILE + t];
        sA[t] = s;
    } else {
        float s = 0.f;
        for (int c = 0; c < NC; ++c) s += normB[(size_t)(b * NC + c) * TILE + (t - TILE)];
        sB[t - TILE] = s;
    }
    __syncthreads();

    for (int i = t; i < 625; i += 256) {
        const int idx = part * 625 + i;           // 0..9999 within batch
        const int n = idx / 100;
        const int k = idx - n * 100;
        float dot = 0.f;
        for (int c = 0; c < NC; ++c)
            dot += dotp[(size_t)(b * NC + c) * (TILE * TILE) + n * TILE + k];
        const float yp = y_p[b * NQ + n];
        const float yg = y_gt[b * NQ + k];
        const float t1 = yp * yg + (1.f - yp) * (1.f - yg);
        out[(size_t)b * (NQ * NQ) + idx] = t1 * (2.f * dot) / (sA[n] + sB[k]);
    }
}

extern "C" void kernel_launch(void* const* d_in, const int* in_sizes, int n_in,
                              void* d_out, int out_size, void* d_ws, size_t ws_size,
                              hipStream_t stream)
{
    const float* y_p  = (const float*)d_in[0];
    const float* y_gt = (const float*)d_in[1];
    const float* m_p  = (const float*)d_in[2];
    const float* m_gt = (const float*)d_in[3];
    float* out = (float*)d_out;

    // pick chunk count that fits the workspace (34 MB at NC=64)
    int NC = 64;
    while (NC > 1) {
        size_t need = (size_t)BQ * NC * (TILE * TILE + 2 * TILE) * sizeof(float);
        if (need <= ws_size) break;
        NC >>= 1;
    }
    const int NIT = (HWP / NC) / KST;

    float* dotp  = (float*)d_ws;
    float* normA = dotp + (size_t)BQ * NC * TILE * TILE;
    float* normB = normA + (size_t)BQ * NC * TILE;

    matcher_gemm<<<dim3(BQ * NC), dim3(512), 0, stream>>>(
        m_p, m_gt, dotp, normA, normB, NC, NIT);
    matcher_finalize<<<dim3(BQ * 16), dim3(256), 0, stream>>>(
        y_p, y_gt, dotp, normA, normB, out, NC);
}

// Round 3
// 193.044 us; speedup vs baseline: 2.1083x; 2.1083x over previous
//
#include <hip/hip_runtime.h>

#define BQ  8
#define NQ  100
#define HWP 65536
#define TILE 128
#define KST  64

typedef float  f32x4  __attribute__((ext_vector_type(4)));
typedef __bf16 bf16x8 __attribute__((ext_vector_type(8)));

struct LD { float4 x, y; };

__device__ __forceinline__ uint32_t pk2(float a, float b) {
    // RNE fp32 -> bf16, packed pair
    uint32_t ua = __builtin_bit_cast(uint32_t, a);
    uint32_t ub = __builtin_bit_cast(uint32_t, b);
    ua += 0x7FFFu + ((ua >> 16) & 1u);
    ub += 0x7FFFu + ((ub >> 16) & 1u);
    return (ua >> 16) | (ub & 0xFFFF0000u);
}

__device__ __forceinline__ LD ldrow(const float* __restrict__ base, int row, int pofs) {
    LD r;
    if (row < NQ) {
        const float4* p = (const float4*)(base + (size_t)row * HWP + pofs);
        r.x = p[0];
        r.y = p[1];
    } else {
        r.x = make_float4(0.f, 0.f, 0.f, 0.f);
        r.y = make_float4(0.f, 0.f, 0.f, 0.f);
    }
    return r;
}

__device__ __forceinline__ void strow(unsigned short* buf, int row, int oct, const LD& v) {
    // XOR swizzle (8-elem granularity) kills 128B-row-stride bank conflicts
    const int col = ((oct ^ (row & 7)) << 3);
    uint4 u;
    u.x = pk2(v.x.x, v.x.y);
    u.y = pk2(v.x.z, v.x.w);
    u.z = pk2(v.y.x, v.y.y);
    u.w = pk2(v.y.z, v.y.w);
    *(uint4*)(buf + row * KST + col) = u;
}

__device__ __forceinline__ float sqsum(const LD& v) {
    return v.x.x*v.x.x + v.x.y*v.x.y + v.x.z*v.x.z + v.x.w*v.x.w
         + v.y.x*v.y.x + v.y.y*v.y.y + v.y.z*v.y.z + v.y.w*v.y.w;
}

// One block = (batch, P-chunk). Padded 128x128 partial Gram tile over its
// 1024-wide chunk + per-row sum-of-squares. 1-deep register prefetch
// (2-deep spilled at R2: VGPR capped 64 -> 900 MB scratch traffic),
// double-buffered LDS, one barrier per K-step, 2 blocks/CU via grid=512.
__global__ __launch_bounds__(512) void matcher_gemm(
    const float* __restrict__ mp, const float* __restrict__ mg,
    float* __restrict__ dotp, float* __restrict__ normA, float* __restrict__ normB,
    int NC, int NIT)
{
    __shared__ __align__(16) unsigned short lds_buf[2][2][TILE * KST];

    const int blk  = blockIdx.x;
    const int b    = blk / NC;
    const int slot = blk - b * NC;
    const int p0   = slot * NIT * KST;

    const int t    = threadIdx.x;
    const int row0 = t >> 3;      // 0..63 (also handles row0+64)
    const int oct  = t & 7;       // 8-float column octant
    const int lane = t & 63;
    const int w    = t >> 6;      // wave 0..7
    const int wr   = w >> 1;      // 0..3 -> 32-row strip
    const int wc   = w & 1;       // 0..1 -> 64-col strip

    const float* Ag = mp + (size_t)b * NQ * HWP;
    const float* Bg = mg + (size_t)b * NQ * HWP;

    f32x4 acc[2][4] = {};
    float nA0 = 0.f, nA1 = 0.f, nB0 = 0.f, nB1 = 0.f;

    LD a0 = ldrow(Ag, row0,      p0 + oct * 8);
    LD a1 = ldrow(Ag, row0 + 64, p0 + oct * 8);
    LD b0 = ldrow(Bg, row0,      p0 + oct * 8);
    LD b1 = ldrow(Bg, row0 + 64, p0 + oct * 8);

    for (int it = 0; it < NIT; ++it) {
        unsigned short* bufA = lds_buf[it & 1][0];
        unsigned short* bufB = lds_buf[it & 1][1];
        strow(bufA, row0,      oct, a0);
        strow(bufA, row0 + 64, oct, a1);
        strow(bufB, row0,      oct, b0);
        strow(bufB, row0 + 64, oct, b1);
        nA0 += sqsum(a0); nA1 += sqsum(a1);
        nB0 += sqsum(b0); nB1 += sqsum(b1);
        if (it + 1 < NIT) {
            // next-iter loads issued BEFORE the barrier: reg-staged loads
            // stay in flight across s_barrier and overlap the MFMA phase
            const int pofs = p0 + (it + 1) * KST + oct * 8;
            a0 = ldrow(Ag, row0,      pofs);
            a1 = ldrow(Ag, row0 + 64, pofs);
            b0 = ldrow(Bg, row0,      pofs);
            b1 = ldrow(Bg, row0 + 64, pofs);
        }
        __syncthreads();

        const unsigned short* rA = lds_buf[it & 1][0];
        const unsigned short* rB = lds_buf[it & 1][1];
        #pragma unroll
        for (int s = 0; s < 2; ++s) {
            bf16x8 af[2];
            bf16x8 bfr[4];
            #pragma unroll
            for (int m = 0; m < 2; ++m) {
                const int row = wr * 32 + m * 16 + (lane & 15);
                const int col = (s * 32 + (lane >> 4) * 8) ^ ((row & 7) << 3);
                af[m] = *(const bf16x8*)(rA + row * KST + col);
            }
            #pragma unroll
            for (int n = 0; n < 4; ++n) {
                const int row = wc * 64 + n * 16 + (lane & 15);
                const int col = (s * 32 + (lane >> 4) * 8) ^ ((row & 7) << 3);
                bfr[n] = *(const bf16x8*)(rB + row * KST + col);
            }
            #pragma unroll
            for (int m = 0; m < 2; ++m)
                #pragma unroll
                for (int n = 0; n < 4; ++n)
                    acc[m][n] = __builtin_amdgcn_mfma_f32_16x16x32_bf16(
                        af[m], bfr[n], acc[m][n], 0, 0, 0);
        }
    }

    // reduce per-row norms across the 8 octant threads (contiguous lanes)
    #pragma unroll
    for (int m = 1; m < 8; m <<= 1) {
        nA0 += __shfl_xor(nA0, m);
        nA1 += __shfl_xor(nA1, m);
        nB0 += __shfl_xor(nB0, m);
        nB1 += __shfl_xor(nB1, m);
    }
    if (oct == 0) {
        float* nap = normA + (size_t)blk * TILE;
        float* nbp = normB + (size_t)blk * TILE;
        nap[row0] = nA0; nap[row0 + 64] = nA1;
        nbp[row0] = nB0; nbp[row0 + 64] = nB1;
    }

    // C/D layout (HW-verified): col = lane&15, row = (lane>>4)*4 + reg
    float* dp = dotp + (size_t)blk * (TILE * TILE);
    const int ccol = lane & 15;
    const int crow = (lane >> 4) * 4;
    #pragma unroll
    for (int m = 0; m < 2; ++m) {
        #pragma unroll
        for (int n = 0; n < 4; ++n) {
            const int gr = wr * 32 + m * 16 + crow;
            const int gc = wc * 64 + n * 16 + ccol;
            #pragma unroll
            for (int j = 0; j < 4; ++j)
                dp[(size_t)(gr + j) * TILE + gc] = acc[m][n][j];
        }
    }
}

// Reduce chunk partials, apply class-agreement term and dice division.
__global__ __launch_bounds__(256) void matcher_finalize(
    const float* __restrict__ y_p, const float* __restrict__ y_gt,
    const float* __restrict__ dotp, const float* __restrict__ normA,
    const float* __restrict__ normB, float* __restrict__ out, int NC)
{
    __shared__ float sA[TILE];
    __shared__ float sB[TILE];
    const int b    = blockIdx.x >> 4;
    const int part = blockIdx.x & 15;
    const int t    = threadIdx.x;

    if (t < TILE) {
        float s = 0.f;
        for (int c = 0; c < NC; ++c) s += normA[(size_t)(b * NC + c) * TILE + t];
        sA[t] = s;
    } else {
        float s = 0.f;
        for (int c = 0; c < NC; ++c) s += normB[(size_t)(b * NC + c) * TILE + (t - TILE)];
        sB[t - TILE] = s;
    }
    __syncthreads();

    for (int i = t; i < 625; i += 256) {
        const int idx = part * 625 + i;           // 0..9999 within batch
        const int n = idx / 100;
        const int k = idx - n * 100;
        float dot = 0.f;
        for (int c = 0; c < NC; ++c)
            dot += dotp[(size_t)(b * NC + c) * (TILE * TILE) + n * TILE + k];
        const float yp = y_p[b * NQ + n];
        const float yg = y_gt[b * NQ + k];
        const float t1 = yp * yg + (1.f - yp) * (1.f - yg);
        out[(size_t)b * (NQ * NQ) + idx] = t1 * (2.f * dot) / (sA[n] + sB[k]);
    }
}

extern "C" void kernel_launch(void* const* d_in, const int* in_sizes, int n_in,
                              void* d_out, int out_size, void* d_ws, size_t ws_size,
                              hipStream_t stream)
{
    const float* y_p  = (const float*)d_in[0];
    const float* y_gt = (const float*)d_in[1];
    const float* m_p  = (const float*)d_in[2];
    const float* m_gt = (const float*)d_in[3];
    float* out = (float*)d_out;

    // pick chunk count that fits the workspace (34 MB at NC=64)
    int NC = 64;
    while (NC > 1) {
        size_t need = (size_t)BQ * NC * (TILE * TILE + 2 * TILE) * sizeof(float);
        if (need <= ws_size) break;
        NC >>= 1;
    }
    const int NIT = (HWP / NC) / KST;

    float* dotp  = (float*)d_ws;
    float* normA = dotp + (size_t)BQ * NC * TILE * TILE;
    float* normB = normA + (size_t)BQ * NC * TILE;

    matcher_gemm<<<dim3(BQ * NC), dim3(512), 0, stream>>>(
        m_p, m_gt, dotp, normA, normB, NC, NIT);
    matcher_finalize<<<dim3(BQ * 16), dim3(256), 0, stream>>>(
        y_p, y_gt, dotp, normA, normB, out, NC);
}

// Round 4
// 157.517 us; speedup vs baseline: 2.5838x; 1.2255x over previous
//
#include <hip/hip_runtime.h>

#define BQ  8
#define NQ  100
#define HWP 65536
#define TILE 128
#define KST  64

typedef float  f32x4  __attribute__((ext_vector_type(4)));
typedef __bf16 bf16x8 __attribute__((ext_vector_type(8)));

struct LD { float4 x, y; };

__device__ __forceinline__ uint32_t pk2(float a, float b) {
    // RNE fp32 -> bf16, packed pair
    uint32_t ua = __builtin_bit_cast(uint32_t, a);
    uint32_t ub = __builtin_bit_cast(uint32_t, b);
    ua += 0x7FFFu + ((ua >> 16) & 1u);
    ub += 0x7FFFu + ((ub >> 16) & 1u);
    return (ua >> 16) | (ub & 0xFFFF0000u);
}

__device__ __forceinline__ LD ldrow(const float* __restrict__ base, int row, int pofs) {
    LD r;
    if (row < NQ) {
        const float4* p = (const float4*)(base + (size_t)row * HWP + pofs);
        r.x = p[0];
        r.y = p[1];
    } else {
        r.x = make_float4(0.f, 0.f, 0.f, 0.f);
        r.y = make_float4(0.f, 0.f, 0.f, 0.f);
    }
    return r;
}

__device__ __forceinline__ void strow(unsigned short* buf, int row, int oct, const LD& v) {
    // XOR swizzle (8-elem granularity) kills 128B-row-stride bank conflicts
    const int col = ((oct ^ (row & 7)) << 3);
    uint4 u;
    u.x = pk2(v.x.x, v.x.y);
    u.y = pk2(v.x.z, v.x.w);
    u.z = pk2(v.y.x, v.y.y);
    u.w = pk2(v.y.z, v.y.w);
    *(uint4*)(buf + row * KST + col) = u;
}

__device__ __forceinline__ float sqsum(const LD& v) {
    return v.x.x*v.x.x + v.x.y*v.x.y + v.x.z*v.x.z + v.x.w*v.x.w
         + v.y.x*v.y.x + v.y.y*v.y.y + v.y.z*v.y.z + v.y.w*v.y.w;
}

// One block = (batch, P-chunk). Padded 128x128 partial Gram tile + row norms.
// Column windows are consumed in a per-block ROTATED order (itc) so the
// instantaneous address stream across blocks spreads over many HBM channels
// instead of aliasing on the 256KB power-of-2 row stride. Sum over K is
// order-independent, so rotation does not change the result.
__global__ __launch_bounds__(512) void matcher_gemm(
    const float* __restrict__ mp, const float* __restrict__ mg,
    float* __restrict__ dotp, float* __restrict__ normA, float* __restrict__ normB,
    int NC, int NIT)
{
    __shared__ __align__(16) unsigned short lds_buf[2][2][TILE * KST];

    const int blk  = blockIdx.x;
    const int b    = blk / NC;
    const int slot = blk - b * NC;
    const int p0   = slot * NIT * KST;
    const int rot  = slot * 5;           // odd multiplier decorrelates slots

    const int t    = threadIdx.x;
    const int row0 = t >> 3;      // 0..63 (also handles row0+64)
    const int oct  = t & 7;       // 8-float column octant
    const int lane = t & 63;
    const int w    = t >> 6;      // wave 0..7
    const int wr   = w >> 1;      // 0..3 -> 32-row strip
    const int wc   = w & 1;       // 0..1 -> 64-col strip

    const float* Ag = mp + (size_t)b * NQ * HWP;
    const float* Bg = mg + (size_t)b * NQ * HWP;

    f32x4 acc[2][4] = {};
    float nA0 = 0.f, nA1 = 0.f, nB0 = 0.f, nB1 = 0.f;

    {
        const int itc = rot & (NIT - 1);
        const int pofs = p0 + itc * KST + oct * 8;
        // (declared below via first loop iteration's operands)
    }

    int itc0 = rot & (NIT - 1);
    LD a0 = ldrow(Ag, row0,      p0 + itc0 * KST + oct * 8);
    LD a1 = ldrow(Ag, row0 + 64, p0 + itc0 * KST + oct * 8);
    LD b0 = ldrow(Bg, row0,      p0 + itc0 * KST + oct * 8);
    LD b1 = ldrow(Bg, row0 + 64, p0 + itc0 * KST + oct * 8);

    for (int it = 0; it < NIT; ++it) {
        unsigned short* bufA = lds_buf[it & 1][0];
        unsigned short* bufB = lds_buf[it & 1][1];
        strow(bufA, row0,      oct, a0);
        strow(bufA, row0 + 64, oct, a1);
        strow(bufB, row0,      oct, b0);
        strow(bufB, row0 + 64, oct, b1);
        nA0 += sqsum(a0); nA1 += sqsum(a1);
        nB0 += sqsum(b0); nB1 += sqsum(b1);
        if (it + 1 < NIT) {
            // next-iter loads issued BEFORE the barrier: reg-staged loads
            // stay in flight across s_barrier and overlap the MFMA phase
            const int itc = (it + 1 + rot) & (NIT - 1);
            const int pofs = p0 + itc * KST + oct * 8;
            a0 = ldrow(Ag, row0,      pofs);
            a1 = ldrow(Ag, row0 + 64, pofs);
            b0 = ldrow(Bg, row0,      pofs);
            b1 = ldrow(Bg, row0 + 64, pofs);
        }
        __syncthreads();

        const unsigned short* rA = lds_buf[it & 1][0];
        const unsigned short* rB = lds_buf[it & 1][1];
        #pragma unroll
        for (int s = 0; s < 2; ++s) {
            bf16x8 af[2];
            bf16x8 bfr[4];
            #pragma unroll
            for (int m = 0; m < 2; ++m) {
                const int row = wr * 32 + m * 16 + (lane & 15);
                const int col = (s * 32 + (lane >> 4) * 8) ^ ((row & 7) << 3);
                af[m] = *(const bf16x8*)(rA + row * KST + col);
            }
            #pragma unroll
            for (int n = 0; n < 4; ++n) {
                const int row = wc * 64 + n * 16 + (lane & 15);
                const int col = (s * 32 + (lane >> 4) * 8) ^ ((row & 7) << 3);
                bfr[n] = *(const bf16x8*)(rB + row * KST + col);
            }
            #pragma unroll
            for (int m = 0; m < 2; ++m)
                #pragma unroll
                for (int n = 0; n < 4; ++n)
                    acc[m][n] = __builtin_amdgcn_mfma_f32_16x16x32_bf16(
                        af[m], bfr[n], acc[m][n], 0, 0, 0);
        }
    }

    // reduce per-row norms across the 8 octant threads (contiguous lanes)
    #pragma unroll
    for (int m = 1; m < 8; m <<= 1) {
        nA0 += __shfl_xor(nA0, m);
        nA1 += __shfl_xor(nA1, m);
        nB0 += __shfl_xor(nB0, m);
        nB1 += __shfl_xor(nB1, m);
    }
    if (oct == 0) {
        float* nap = normA + (size_t)blk * TILE;
        float* nbp = normB + (size_t)blk * TILE;
        nap[row0] = nA0; nap[row0 + 64] = nA1;
        nbp[row0] = nB0; nbp[row0 + 64] = nB1;
    }

    // C/D layout (HW-verified): col = lane&15, row = (lane>>4)*4 + reg
    float* dp = dotp + (size_t)blk * (TILE * TILE);
    const int ccol = lane & 15;
    const int crow = (lane >> 4) * 4;
    #pragma unroll
    for (int m = 0; m < 2; ++m) {
        #pragma unroll
        for (int n = 0; n < 4; ++n) {
            const int gr = wr * 32 + m * 16 + crow;
            const int gc = wc * 64 + n * 16 + ccol;
            #pragma unroll
            for (int j = 0; j < 4; ++j)
                dp[(size_t)(gr + j) * TILE + gc] = acc[m][n][j];
        }
    }
}

// Reduce chunk partials, apply class-agreement term and dice division.
__global__ __launch_bounds__(256) void matcher_finalize(
    const float* __restrict__ y_p, const float* __restrict__ y_gt,
    const float* __restrict__ dotp, const float* __restrict__ normA,
    const float* __restrict__ normB, float* __restrict__ out, int NC)
{
    __shared__ float sA[TILE];
    __shared__ float sB[TILE];
    const int b    = blockIdx.x >> 4;
    const int part = blockIdx.x & 15;
    const int t    = threadIdx.x;

    if (t < TILE) {
        float s = 0.f;
        for (int c = 0; c < NC; ++c) s += normA[(size_t)(b * NC + c) * TILE + t];
        sA[t] = s;
    } else {
        float s = 0.f;
        for (int c = 0; c < NC; ++c) s += normB[(size_t)(b * NC + c) * TILE + (t - TILE)];
        sB[t - TILE] = s;
    }
    __syncthreads();

    for (int i = t; i < 625; i += 256) {
        const int idx = part * 625 + i;           // 0..9999 within batch
        const int n = idx / 100;
        const int k = idx - n * 100;
        float dot = 0.f;
        for (int c = 0; c < NC; ++c)
            dot += dotp[(size_t)(b * NC + c) * (TILE * TILE) + n * TILE + k];
        const float yp = y_p[b * NQ + n];
        const float yg = y_gt[b * NQ + k];
        const float t1 = yp * yg + (1.f - yp) * (1.f - yg);
        out[(size_t)b * (NQ * NQ) + idx] = t1 * (2.f * dot) / (sA[n] + sB[k]);
    }
}

extern "C" void kernel_launch(void* const* d_in, const int* in_sizes, int n_in,
                              void* d_out, int out_size, void* d_ws, size_t ws_size,
                              hipStream_t stream)
{
    const float* y_p  = (const float*)d_in[0];
    const float* y_gt = (const float*)d_in[1];
    const float* m_p  = (const float*)d_in[2];
    const float* m_gt = (const float*)d_in[3];
    float* out = (float*)d_out;

    // grid = 1 block/CU; NIT must stay a power of two for the rotation mask
    int NC = 32;
    while (NC > 1) {
        size_t need = (size_t)BQ * NC * (TILE * TILE + 2 * TILE) * sizeof(float);
        if (need <= ws_size) break;
        NC >>= 1;
    }
    const int NIT = (HWP / NC) / KST;

    float* dotp  = (float*)d_ws;
    float* normA = dotp + (size_t)BQ * NC * TILE * TILE;
    float* normB = normA + (size_t)BQ * NC * TILE;

    matcher_gemm<<<dim3(BQ * NC), dim3(512), 0, stream>>>(
        m_p, m_gt, dotp, normA, normB, NC, NIT);
    matcher_finalize<<<dim3(BQ * 16), dim3(256), 0, stream>>>(
        y_p, y_gt, dotp, normA, normB, out, NC);
}